// Round 5
// baseline (267.486 us; speedup 1.0000x reference)
//
#include <hip/hip_runtime.h>
#include <hip/hip_bf16.h>

#define D 64
#define KCODES 1024
// Approx-path error budget (distance units):
//   bf16 hi/lo split residual (proven <=0.025 in prior session at MARGIN=0.25)
// + MFMA accumulation rounding at magnitude ~2048-5700 (C-init biased): <=0.10 worst
// + split-chain join add (new): <=0.01
// + key quantization 2 x 63*ULP(<2^13) = 2 x 0.031
// => 2*eps <= ~0.40 < MARGIN. Flags ~1% of rows, handled exactly by rescore.
// This scheme PASSED on HW with absmax=0.0 (round 3).
#define MARGIN 0.6f
#define OFFSET 2048.0f   // makes approx distance strictly positive => uint-sortable bits

typedef __attribute__((ext_vector_type(8))) short bf16x8;
typedef __attribute__((ext_vector_type(4))) float f32x4;

__device__ __forceinline__ unsigned short f2bf(float f) {
    union { __hip_bfloat16 h; unsigned short s; } cv;
    cv.h = __float2bfloat16(f);
    return cv.s;
}
__device__ __forceinline__ float bf2f(unsigned short v) {
    union { unsigned short s; __hip_bfloat16 h; } cv;
    cv.s = v;
    return __bfloat162float(cv.h);
}

// k0: e2[k] = ||e_k||^2 (exact, same summation as proven round-2 arithmetic),
// e2b[k] = e2[k] + OFFSET (approx path only), bf16 hi/lo split, zero counter.
__global__ __launch_bounds__(256) void prep_kernel(
    const float* __restrict__ emb, float* __restrict__ e2, float* __restrict__ e2b,
    unsigned short* __restrict__ ehi, unsigned short* __restrict__ elo,
    unsigned int* __restrict__ counter) {
    int t = blockIdx.x * 256 + threadIdx.x;
    if (t == 0) *counter = 0u;
    if (t < KCODES) {
        const float4* ep = (const float4*)(emb + (size_t)t * D);
        float s0 = 0.f, s1 = 0.f, s2 = 0.f, s3 = 0.f;
#pragma unroll
        for (int i = 0; i < 16; ++i) {
            float4 v = ep[i];
            s0 = fmaf(v.x, v.x, s0);
            s1 = fmaf(v.y, v.y, s1);
            s2 = fmaf(v.z, v.z, s2);
            s3 = fmaf(v.w, v.w, s3);
        }
        float s = (s0 + s1) + (s2 + s3);
        e2[t] = s;           // exact, used by rescore (unchanged arithmetic)
        e2b[t] = s + OFFSET; // biased, approx path / MFMA C-init
    }
    float v = emb[t];
    unsigned short h = f2bf(v);
    ehi[t] = h;
    elo[t] = f2bf(v - bf2f(h));
}

// k1: MFMA distance argmin.
// Block = 4 waves x 32 rows = 128 rows; grid 1024 => 4 blocks/CU.
// ROUND-4 RESTRUCTURE (m233 lesson: tiny compute phases between full-drain
// barriers were ~4000 cyc/phase for ~60 cyc of MFMA):
//   - 4-tile groups: 16 barrier phases (was 64), 48 MFMA/wave/phase (was 12).
//   - LDS: 2 buffers x 16KB (4 tiles x (hi 2KB | lo 2KB)), XOR-swizzled rows.
//   - per-tile MFMA chain split into 2 independent chains of 3 (chunk0 carries
//     the e2b C-init; chunk1 starts at 0; one f32 add joins) -> 4 indep chains
//     per wave per tile for MFMA-latency hiding.
//   - T14 split: global->reg stage loads + next-group e2b issued at phase top,
//     ds_write just before the single barrier per phase.
// Distance d = e2b - 2 x.e > 0 => bits uint-sortable. key = (bits & ~63)|tile.
// Top-2: m1 = min_u32(m1,key); m2 = v_med3_u32(m1_old,m2,key). [HW-validated]
__global__ __launch_bounds__(256, 4) void vq_mfma_kernel(
    const float* __restrict__ x, const float* __restrict__ emb,
    const float* __restrict__ e2b, const unsigned short* __restrict__ ehi,
    const unsigned short* __restrict__ elo, float* __restrict__ out_q,
    float* __restrict__ out_idx, float* __restrict__ out_loss,
    unsigned int* __restrict__ counter, int* __restrict__ flaglist, int flag_cap) {
    __shared__ float4 lds4[2][1024];   // 2 x 16KB
    __shared__ int s_bi[128];
    char* ldsc = (char*)&lds4[0][0];
    const int tid = threadIdx.x;
    const int lane = tid & 63;
    const int wave = __builtin_amdgcn_readfirstlane(tid >> 6);
    const int quad = lane >> 4;
    const int l15 = lane & 15;
    const int rowBase = blockIdx.x * 128 + wave * 32;

    // A fragments: 2 rowsets x 16 rows, pre-scaled by -2, bf16 hi/lo.
    bf16x8 ah[2][2], al[2][2];
#pragma unroll
    for (int rs = 0; rs < 2; ++rs) {
        const float* xr = x + (size_t)(rowBase + rs * 16 + l15) * D;
#pragma unroll
        for (int c = 0; c < 2; ++c) {
            const float4* p = (const float4*)(xr + c * 32 + quad * 8);
            float4 f0 = p[0], f1 = p[1];
            float f[8] = {f0.x, f0.y, f0.z, f0.w, f1.x, f1.y, f1.z, f1.w};
            bf16x8 h, l;
#pragma unroll
            for (int j = 0; j < 8; ++j) {
                float v = -2.0f * f[j];             // exact scale
                unsigned short hu = f2bf(v);
                h[j] = (short)hu;
                l[j] = (short)f2bf(v - bf2f(hu));   // exact (Sterbenz)
            }
            ah[rs][c] = h;
            al[rs][c] = l;
        }
    }

    // Staging map: 1024 x 16B slots per group = [h:2][row:64][slot:8].
    // idx = tid + 256*j (j=0..3) -> bijective. Linear global read, swizzled
    // LDS write: 16B slot p of row r stored at p^(r&7) (rule #21 both-sides).
    const unsigned short* gsrc[4];
    int ldst[4];
#pragma unroll
    for (int j = 0; j < 4; ++j) {
        int idx = tid + 256 * j;
        int h = idx >> 9, r = (idx >> 3) & 63, sl = idx & 7;
        gsrc[j] = (h ? elo : ehi) + r * 64 + sl * 8;
        ldst[j] = h * 8192 + r * 128 + ((sl ^ (r & 7)) << 4);
    }

    // ds_read offsets (swizzled): tile tg row = tg*16 + l15; (tg*16)&7 == 0 so
    // the XOR key stays l15&7. Chunk c=0 slot quad, c=1 slot quad+4; lo +8192.
    const int s7 = l15 & 7;
    const int rdA0 = l15 * 128 + ((quad ^ s7) << 4);
    const int rdB0 = l15 * 128 + (((quad + 4) ^ s7) << 4);

    unsigned int m1[2][4], m2[2][4];
#pragma unroll
    for (int rs = 0; rs < 2; ++rs)
#pragma unroll
        for (int r = 0; r < 4; ++r) { m1[rs][r] = 0xFFFFFFFFu; m2[rs][r] = 0xFFFFFFFFu; }

    // Prologue: stage group 0 -> buf0; load group-0 e2b.
    float e2v[4];
#pragma unroll
    for (int j = 0; j < 4; ++j) {
        float4 v = *(const float4*)gsrc[j];
        *(float4*)(ldsc + ldst[j]) = v;
    }
#pragma unroll
    for (int tg = 0; tg < 4; ++tg) e2v[tg] = e2b[tg * 16 + l15];
    __syncthreads();

#pragma unroll 1
    for (int g = 0; g < 16; ++g) {
        // Phase top: issue next-group stage loads + e2b prefetch (T14 split).
        float4 st[4];
        float e2n[4];
        if (g < 15) {
#pragma unroll
            for (int j = 0; j < 4; ++j)
                st[j] = *(const float4*)(gsrc[j] + (size_t)(g + 1) * 4096);
#pragma unroll
            for (int tg = 0; tg < 4; ++tg)
                e2n[tg] = e2b[(g + 1) * 64 + tg * 16 + l15];
        }
        const char* rb = ldsc + (g & 1) * 16384;
#pragma unroll
        for (int tg = 0; tg < 4; ++tg) {
            bf16x8 bh0 = *(const bf16x8*)(rb + rdA0 + tg * 2048);
            bf16x8 bh1 = *(const bf16x8*)(rb + rdB0 + tg * 2048);
            bf16x8 bl0 = *(const bf16x8*)(rb + 8192 + rdA0 + tg * 2048);
            bf16x8 bl1 = *(const bf16x8*)(rb + 8192 + rdB0 + tg * 2048);
            const unsigned tt = (unsigned)(g * 4 + tg);
            const float ev = e2v[tg];
            f32x4 c0 = {ev, ev, ev, ev};   // C-init: col(code)=l15, all 4 rows
#pragma unroll
            for (int rs = 0; rs < 2; ++rs) {
                // Two independent 3-MFMA chains (chunk0 carries C-init).
                f32x4 a0 = c0;
                f32x4 a1 = {0.f, 0.f, 0.f, 0.f};
                a0 = __builtin_amdgcn_mfma_f32_16x16x32_bf16(ah[rs][0], bh0, a0, 0, 0, 0);
                a1 = __builtin_amdgcn_mfma_f32_16x16x32_bf16(ah[rs][1], bh1, a1, 0, 0, 0);
                a0 = __builtin_amdgcn_mfma_f32_16x16x32_bf16(al[rs][0], bh0, a0, 0, 0, 0);
                a1 = __builtin_amdgcn_mfma_f32_16x16x32_bf16(al[rs][1], bh1, a1, 0, 0, 0);
                a0 = __builtin_amdgcn_mfma_f32_16x16x32_bf16(ah[rs][0], bl0, a0, 0, 0, 0);
                a1 = __builtin_amdgcn_mfma_f32_16x16x32_bf16(ah[rs][1], bl1, a1, 0, 0, 0);
#pragma unroll
                for (int r = 0; r < 4; ++r) {
                    float v = a0[r] + a1[r];
                    unsigned k = (__float_as_uint(v) & 0xFFFFFFC0u) | tt;
                    unsigned nm2;
                    asm("v_med3_u32 %0, %1, %2, %3"
                        : "=v"(nm2)
                        : "v"(m1[rs][r]), "v"(m2[rs][r]), "v"(k));
                    m2[rs][r] = nm2;                       // exact new 2nd-min
                    m1[rs][r] = (k < m1[rs][r]) ? k : m1[rs][r];
                }
            }
        }
        // Phase bottom: commit next-group stage to the other buffer, barrier.
        if (g < 15) {
            char* wb = ldsc + ((g + 1) & 1) * 16384;
#pragma unroll
            for (int j = 0; j < 4; ++j) *(float4*)(wb + ldst[j]) = st[j];
#pragma unroll
            for (int tg = 0; tg < 4; ++tg) e2v[tg] = e2n[tg];
        }
        __syncthreads();
    }

    // Cross-lane merge over the 16 code-lanes; recover winner lane via ballot.
    // Near-ties (incl. all key-level ties) satisfy m2-m1 < MARGIN => rescored
    // exactly, so tie-break here need not match the reference.
#pragma unroll
    for (int rs = 0; rs < 2; ++rs)
#pragma unroll
        for (int r = 0; r < 4; ++r) {
            unsigned v1 = m1[rs][r], v2 = m2[rs][r];
            const unsigned my1 = v1;
#pragma unroll
            for (int mask = 1; mask < 16; mask <<= 1) {
                unsigned o1 = __shfl_xor(v1, mask);
                unsigned o2 = __shfl_xor(v2, mask);
                unsigned hi = v1 > o1 ? v1 : o1;
                unsigned lo2 = v2 < o2 ? v2 : o2;
                v2 = lo2 < hi ? lo2 : hi;   // union 2nd-min
                v1 = v1 < o1 ? v1 : o1;
            }
            unsigned long long bal = __ballot(my1 == v1);
            int winl = __ffsll((bal >> (quad * 16)) & 0xFFFFull) - 1;
            int code = (int)(v1 & 63u) * 16 + winl;
            if (l15 == 0) {
                int lrow = wave * 32 + rs * 16 + quad * 4 + r;
                s_bi[lrow] = code;
                float f1 = __uint_as_float(v1 & 0xFFFFFFC0u);
                float f2 = __uint_as_float(v2 & 0xFFFFFFC0u);
                if (f2 - f1 < MARGIN) {
                    unsigned slot = atomicAdd(counter, 1u);
                    if (slot < (unsigned)flag_cap) flaglist[slot] = blockIdx.x * 128 + lrow;
                }
            }
        }
    __syncthreads();

    // Fused epilogue: arithmetic kept verbatim from the proven version.
    if (tid < 128) {
        const int row = blockIdx.x * 128 + tid;
        const int bi = s_bi[tid];
        const float4* qp = (const float4*)(emb + (size_t)bi * D);
        const float4* xp = (const float4*)(x + (size_t)row * D);
        float4* oq = (float4*)(out_q + (size_t)row * D);
        float l0 = 0.f, l1 = 0.f, l2 = 0.f, l3 = 0.f;
#pragma unroll
        for (int i = 0; i < 16; ++i) {
            float4 q = qp[i];
            float4 xv = xp[i];
            float a0 = q.x - xv.x, a1 = q.y - xv.y, a2 = q.z - xv.z, a3 = q.w - xv.w;
            l0 = fmaf(a0, a0, l0);
            l1 = fmaf(a1, a1, l1);
            l2 = fmaf(a2, a2, l2);
            l3 = fmaf(a3, a3, l3);
            float4 o;
            o.x = xv.x + a0;
            o.y = xv.y + a1;
            o.z = xv.z + a2;
            o.w = xv.w + a3;
            oq[i] = o;
        }
        float s = (l0 + l1) + (l2 + l3);
        out_idx[row] = (float)bi;
        out_loss[row] = s + 0.25f * s;
    }
}

// k2: exact fp32 rescore of flagged rows, 8 rows per block-batch so the 256KB
// codebook is swept once per 8 rows (8x less L2 traffic than row-at-a-time).
// Per-(row,code) arithmetic is bit-identical to the proven round-2 formula.
__global__ __launch_bounds__(256) void rescore_kernel(
    const float* __restrict__ x, const float* __restrict__ emb,
    const float* __restrict__ e2, float* __restrict__ out_q,
    float* __restrict__ out_idx, float* __restrict__ out_loss,
    const unsigned int* __restrict__ counter, const int* __restrict__ flaglist,
    int flag_cap) {
    __shared__ float s_x[8][64];
    __shared__ int s_rows[8];
    __shared__ float s_wd[8][4];
    __shared__ int s_wi[8][4];
    __shared__ float s_a[4][64];
    unsigned int n = *counter;
    if (n > (unsigned)flag_cap) n = (unsigned)flag_cap;
    const int tid = threadIdx.x;
    const int lane = tid & 63;
    const int wv = tid >> 6;
    for (unsigned int b = blockIdx.x; b * 8u < n; b += gridDim.x) {
        const unsigned base = b * 8u;
        unsigned nbu = n - base;
        if (nbu > 8u) nbu = 8u;
        const int nb = (int)nbu;
        if (tid < 8) s_rows[tid] = flaglist[base + (tid < nb ? tid : 0)];
        __syncthreads();
        if (tid < 128) {
            int r = tid >> 4, q4 = tid & 15;
            ((float4*)&s_x[r][0])[q4] = ((const float4*)(x + (size_t)s_rows[r] * D))[q4];
        }
        __syncthreads();

        float bd_[8];
        int bi_[8];
#pragma unroll
        for (int r = 0; r < 8; ++r) { bd_[r] = 3.4e38f; bi_[r] = 0; }
        for (int kk = 0; kk < 4; ++kk) {
            const int k = tid + kk * 256;   // ascending per thread
            const float* ek = emb + (size_t)k * D;
            float d0[8], d1[8], d2[8], d3[8];
#pragma unroll
            for (int r = 0; r < 8; ++r) { d0[r] = 0.f; d1[r] = 0.f; d2[r] = 0.f; d3[r] = 0.f; }
#pragma unroll
            for (int i = 0; i < 16; ++i) {
                float4 ev = ((const float4*)ek)[i];
#pragma unroll
                for (int r = 0; r < 8; ++r) {
                    float4 xv = ((const float4*)&s_x[r][0])[i];   // LDS broadcast
                    d0[r] = fmaf(xv.x, ev.x, d0[r]);
                    d1[r] = fmaf(xv.y, ev.y, d1[r]);
                    d2[r] = fmaf(xv.z, ev.z, d2[r]);
                    d3[r] = fmaf(xv.w, ev.w, d3[r]);
                }
            }
            float e2k = e2[k];
#pragma unroll
            for (int r = 0; r < 8; ++r) {
                float dist = fmaf(-2.0f, (d0[r] + d1[r]) + (d2[r] + d3[r]), e2k);
                if (dist < bd_[r]) { bd_[r] = dist; bi_[r] = k; }
            }
        }
        // reduce: wave shuffle then cross-wave, lexicographic (dist, index)
#pragma unroll
        for (int r = 0; r < 8; ++r) {
            float v = bd_[r];
            int ix = bi_[r];
#pragma unroll
            for (int mask = 1; mask < 64; mask <<= 1) {
                float ov = __shfl_xor(v, mask);
                int oi = __shfl_xor(ix, mask);
                bool tk = (ov < v) || (ov == v && oi < ix);
                v = tk ? ov : v;
                ix = tk ? oi : ix;
            }
            if (lane == 0) { s_wd[r][wv] = v; s_wi[r][wv] = ix; }
        }
        __syncthreads();
        if (tid < 8) {
            float v = s_wd[tid][0];
            int ix = s_wi[tid][0];
#pragma unroll
            for (int w = 1; w < 4; ++w) {
                float ov = s_wd[tid][w];
                int oi = s_wi[tid][w];
                bool tk = (ov < v) || (ov == v && oi < ix);
                v = tk ? ov : v;
                ix = tk ? oi : ix;
            }
            s_wi[tid][0] = ix;
        }
        __syncthreads();
        // epilogue: 2 passes x 4 rows; original per-element + summation order.
#pragma unroll
        for (int pass = 0; pass < 2; ++pass) {
            const int rloc = pass * 4 + wv;
            const int row = s_rows[rloc];
            const int fbi = s_wi[rloc][0];
            const float xe = s_x[rloc][lane];
            const float a = emb[(size_t)fbi * D + lane] - xe;
            if (rloc < nb) out_q[(size_t)row * D + lane] = xe + a;
            s_a[wv][lane] = a * a;
            __syncthreads();
            if (lane == 0 && rloc < nb) {
                float l0 = 0.f, l1 = 0.f, l2 = 0.f, l3 = 0.f;
                for (int i2 = 0; i2 < 16; ++i2) {
                    l0 += s_a[wv][4 * i2 + 0];
                    l1 += s_a[wv][4 * i2 + 1];
                    l2 += s_a[wv][4 * i2 + 2];
                    l3 += s_a[wv][4 * i2 + 3];
                }
                float s = (l0 + l1) + (l2 + l3);
                out_loss[row] = s + 0.25f * s;
                out_idx[row] = (float)fbi;
            }
            __syncthreads();
        }
    }
}

extern "C" void kernel_launch(void* const* d_in, const int* in_sizes, int n_in,
                              void* d_out, int out_size, void* d_ws, size_t ws_size,
                              hipStream_t stream) {
    const float* x = (const float*)d_in[0];     // [B,T,D] fp32
    const float* emb = (const float*)d_in[1];   // [K,D] fp32
    const int nrows = in_sizes[0] / D;          // 131072

    float* out_q = (float*)d_out;
    float* out_idx = out_q + (size_t)nrows * D;
    float* out_loss = out_idx + nrows;

    // ws: e2 4KB | e2b 4KB | ehi 128KB | elo 128KB | counter 64B | flaglist
    char* ws = (char*)d_ws;
    float* e2 = (float*)ws;
    float* e2b = (float*)(ws + 4096);
    unsigned short* ehi = (unsigned short*)(ws + 8192);
    unsigned short* elo = (unsigned short*)(ws + 8192 + 131072);
    unsigned int* counter = (unsigned int*)(ws + 8192 + 262144);
    int* flaglist = (int*)(ws + 8192 + 262144 + 64);
    long long avail = (long long)ws_size - (8192 + 262144 + 64);
    int flag_cap = (int)(avail / 4);
    if (flag_cap > 16384) flag_cap = 16384;
    if (flag_cap < 1024) flag_cap = 1024;

    prep_kernel<<<(KCODES * D) / 256, 256, 0, stream>>>(emb, e2, e2b, ehi, elo, counter);
    vq_mfma_kernel<<<nrows / 128, 256, 0, stream>>>(x, emb, e2b, ehi, elo, out_q,
                                                    out_idx, out_loss, counter,
                                                    flaglist, flag_cap);
    rescore_kernel<<<1024, 256, 0, stream>>>(x, emb, e2, out_q, out_idx, out_loss,
                                             counter, flaglist, flag_cap);
}

// Round 6
// 264.400 us; speedup vs baseline: 1.0117x; 1.0117x over previous
//
#include <hip/hip_runtime.h>
#include <hip/hip_bf16.h>

#define D 64
#define KCODES 1024
// Approx-path error budget (distance units):
//   bf16 hi/lo split residual (proven <=0.025 in prior session at MARGIN=0.25)
// + MFMA accumulation rounding at magnitude ~2048-5700 (C-init biased): <=0.10 worst
// + split-chain join add: <=0.01
// + key quantization 2 x 63*ULP(<2^13) = 2 x 0.031
// => 2*eps <= ~0.40 < MARGIN. Flags ~1% of rows, handled exactly by rescore.
// This scheme PASSED on HW with absmax=0.0 (rounds 3 and 5).
#define MARGIN 0.6f
#define OFFSET 2048.0f   // makes approx distance strictly positive => uint-sortable bits

typedef __attribute__((ext_vector_type(8))) short bf16x8;
typedef __attribute__((ext_vector_type(4))) float f32x4;

__device__ __forceinline__ unsigned short f2bf(float f) {
    union { __hip_bfloat16 h; unsigned short s; } cv;
    cv.h = __float2bfloat16(f);
    return cv.s;
}
__device__ __forceinline__ float bf2f(unsigned short v) {
    union { unsigned short s; __hip_bfloat16 h; } cv;
    cv.s = v;
    return __bfloat162float(cv.h);
}

// k0: e2[k] = ||e_k||^2 (exact, same summation as proven round-2 arithmetic),
// e2b[k] = e2[k] + OFFSET (approx path only), bf16 hi/lo split, zero counter.
__global__ __launch_bounds__(256) void prep_kernel(
    const float* __restrict__ emb, float* __restrict__ e2, float* __restrict__ e2b,
    unsigned short* __restrict__ ehi, unsigned short* __restrict__ elo,
    unsigned int* __restrict__ counter) {
    int t = blockIdx.x * 256 + threadIdx.x;
    if (t == 0) *counter = 0u;
    if (t < KCODES) {
        const float4* ep = (const float4*)(emb + (size_t)t * D);
        float s0 = 0.f, s1 = 0.f, s2 = 0.f, s3 = 0.f;
#pragma unroll
        for (int i = 0; i < 16; ++i) {
            float4 v = ep[i];
            s0 = fmaf(v.x, v.x, s0);
            s1 = fmaf(v.y, v.y, s1);
            s2 = fmaf(v.z, v.z, s2);
            s3 = fmaf(v.w, v.w, s3);
        }
        float s = (s0 + s1) + (s2 + s3);
        e2[t] = s;           // exact, used by rescore (unchanged arithmetic)
        e2b[t] = s + OFFSET; // biased, approx path / MFMA C-init
    }
    float v = emb[t];
    unsigned short h = f2bf(v);
    ehi[t] = h;
    elo[t] = f2bf(v - bf2f(h));
}

// k1: MFMA distance argmin — BYTE-IDENTICAL to the measured round-5 version
// (112 µs, absmax 0.0). Kept unchanged this round to isolate the rescore fix.
__global__ __launch_bounds__(256, 4) void vq_mfma_kernel(
    const float* __restrict__ x, const float* __restrict__ emb,
    const float* __restrict__ e2b, const unsigned short* __restrict__ ehi,
    const unsigned short* __restrict__ elo, float* __restrict__ out_q,
    float* __restrict__ out_idx, float* __restrict__ out_loss,
    unsigned int* __restrict__ counter, int* __restrict__ flaglist, int flag_cap) {
    __shared__ float4 lds4[2][1024];   // 2 x 16KB
    __shared__ int s_bi[128];
    char* ldsc = (char*)&lds4[0][0];
    const int tid = threadIdx.x;
    const int lane = tid & 63;
    const int wave = __builtin_amdgcn_readfirstlane(tid >> 6);
    const int quad = lane >> 4;
    const int l15 = lane & 15;
    const int rowBase = blockIdx.x * 128 + wave * 32;

    // A fragments: 2 rowsets x 16 rows, pre-scaled by -2, bf16 hi/lo.
    bf16x8 ah[2][2], al[2][2];
#pragma unroll
    for (int rs = 0; rs < 2; ++rs) {
        const float* xr = x + (size_t)(rowBase + rs * 16 + l15) * D;
#pragma unroll
        for (int c = 0; c < 2; ++c) {
            const float4* p = (const float4*)(xr + c * 32 + quad * 8);
            float4 f0 = p[0], f1 = p[1];
            float f[8] = {f0.x, f0.y, f0.z, f0.w, f1.x, f1.y, f1.z, f1.w};
            bf16x8 h, l;
#pragma unroll
            for (int j = 0; j < 8; ++j) {
                float v = -2.0f * f[j];             // exact scale
                unsigned short hu = f2bf(v);
                h[j] = (short)hu;
                l[j] = (short)f2bf(v - bf2f(hu));   // exact (Sterbenz)
            }
            ah[rs][c] = h;
            al[rs][c] = l;
        }
    }

    // Staging map: 1024 x 16B slots per group = [h:2][row:64][slot:8].
    // idx = tid + 256*j (j=0..3) -> bijective. Linear global read, swizzled
    // LDS write: 16B slot p of row r stored at p^(r&7) (rule #21 both-sides).
    const unsigned short* gsrc[4];
    int ldst[4];
#pragma unroll
    for (int j = 0; j < 4; ++j) {
        int idx = tid + 256 * j;
        int h = idx >> 9, r = (idx >> 3) & 63, sl = idx & 7;
        gsrc[j] = (h ? elo : ehi) + r * 64 + sl * 8;
        ldst[j] = h * 8192 + r * 128 + ((sl ^ (r & 7)) << 4);
    }

    // ds_read offsets (swizzled): tile tg row = tg*16 + l15; (tg*16)&7 == 0 so
    // the XOR key stays l15&7. Chunk c=0 slot quad, c=1 slot quad+4; lo +8192.
    const int s7 = l15 & 7;
    const int rdA0 = l15 * 128 + ((quad ^ s7) << 4);
    const int rdB0 = l15 * 128 + (((quad + 4) ^ s7) << 4);

    unsigned int m1[2][4], m2[2][4];
#pragma unroll
    for (int rs = 0; rs < 2; ++rs)
#pragma unroll
        for (int r = 0; r < 4; ++r) { m1[rs][r] = 0xFFFFFFFFu; m2[rs][r] = 0xFFFFFFFFu; }

    // Prologue: stage group 0 -> buf0; load group-0 e2b.
    float e2v[4];
#pragma unroll
    for (int j = 0; j < 4; ++j) {
        float4 v = *(const float4*)gsrc[j];
        *(float4*)(ldsc + ldst[j]) = v;
    }
#pragma unroll
    for (int tg = 0; tg < 4; ++tg) e2v[tg] = e2b[tg * 16 + l15];
    __syncthreads();

#pragma unroll 1
    for (int g = 0; g < 16; ++g) {
        // Phase top: issue next-group stage loads + e2b prefetch (T14 split).
        float4 st[4];
        float e2n[4];
        if (g < 15) {
#pragma unroll
            for (int j = 0; j < 4; ++j)
                st[j] = *(const float4*)(gsrc[j] + (size_t)(g + 1) * 4096);
#pragma unroll
            for (int tg = 0; tg < 4; ++tg)
                e2n[tg] = e2b[(g + 1) * 64 + tg * 16 + l15];
        }
        const char* rb = ldsc + (g & 1) * 16384;
#pragma unroll
        for (int tg = 0; tg < 4; ++tg) {
            bf16x8 bh0 = *(const bf16x8*)(rb + rdA0 + tg * 2048);
            bf16x8 bh1 = *(const bf16x8*)(rb + rdB0 + tg * 2048);
            bf16x8 bl0 = *(const bf16x8*)(rb + 8192 + rdA0 + tg * 2048);
            bf16x8 bl1 = *(const bf16x8*)(rb + 8192 + rdB0 + tg * 2048);
            const unsigned tt = (unsigned)(g * 4 + tg);
            const float ev = e2v[tg];
            f32x4 c0 = {ev, ev, ev, ev};   // C-init: col(code)=l15, all 4 rows
#pragma unroll
            for (int rs = 0; rs < 2; ++rs) {
                // Two independent 3-MFMA chains (chunk0 carries C-init).
                f32x4 a0 = c0;
                f32x4 a1 = {0.f, 0.f, 0.f, 0.f};
                a0 = __builtin_amdgcn_mfma_f32_16x16x32_bf16(ah[rs][0], bh0, a0, 0, 0, 0);
                a1 = __builtin_amdgcn_mfma_f32_16x16x32_bf16(ah[rs][1], bh1, a1, 0, 0, 0);
                a0 = __builtin_amdgcn_mfma_f32_16x16x32_bf16(al[rs][0], bh0, a0, 0, 0, 0);
                a1 = __builtin_amdgcn_mfma_f32_16x16x32_bf16(al[rs][1], bh1, a1, 0, 0, 0);
                a0 = __builtin_amdgcn_mfma_f32_16x16x32_bf16(ah[rs][0], bl0, a0, 0, 0, 0);
                a1 = __builtin_amdgcn_mfma_f32_16x16x32_bf16(ah[rs][1], bl1, a1, 0, 0, 0);
#pragma unroll
                for (int r = 0; r < 4; ++r) {
                    float v = a0[r] + a1[r];
                    unsigned k = (__float_as_uint(v) & 0xFFFFFFC0u) | tt;
                    unsigned nm2;
                    asm("v_med3_u32 %0, %1, %2, %3"
                        : "=v"(nm2)
                        : "v"(m1[rs][r]), "v"(m2[rs][r]), "v"(k));
                    m2[rs][r] = nm2;                       // exact new 2nd-min
                    m1[rs][r] = (k < m1[rs][r]) ? k : m1[rs][r];
                }
            }
        }
        // Phase bottom: commit next-group stage to the other buffer, barrier.
        if (g < 15) {
            char* wb = ldsc + ((g + 1) & 1) * 16384;
#pragma unroll
            for (int j = 0; j < 4; ++j) *(float4*)(wb + ldst[j]) = st[j];
#pragma unroll
            for (int tg = 0; tg < 4; ++tg) e2v[tg] = e2n[tg];
        }
        __syncthreads();
    }

    // Cross-lane merge over the 16 code-lanes; recover winner lane via ballot.
    // Near-ties (incl. all key-level ties) satisfy m2-m1 < MARGIN => rescored
    // exactly, so tie-break here need not match the reference.
#pragma unroll
    for (int rs = 0; rs < 2; ++rs)
#pragma unroll
        for (int r = 0; r < 4; ++r) {
            unsigned v1 = m1[rs][r], v2 = m2[rs][r];
            const unsigned my1 = v1;
#pragma unroll
            for (int mask = 1; mask < 16; mask <<= 1) {
                unsigned o1 = __shfl_xor(v1, mask);
                unsigned o2 = __shfl_xor(v2, mask);
                unsigned hi = v1 > o1 ? v1 : o1;
                unsigned lo2 = v2 < o2 ? v2 : o2;
                v2 = lo2 < hi ? lo2 : hi;   // union 2nd-min
                v1 = v1 < o1 ? v1 : o1;
            }
            unsigned long long bal = __ballot(my1 == v1);
            int winl = __ffsll((bal >> (quad * 16)) & 0xFFFFull) - 1;
            int code = (int)(v1 & 63u) * 16 + winl;
            if (l15 == 0) {
                int lrow = wave * 32 + rs * 16 + quad * 4 + r;
                s_bi[lrow] = code;
                float f1 = __uint_as_float(v1 & 0xFFFFFFC0u);
                float f2 = __uint_as_float(v2 & 0xFFFFFFC0u);
                if (f2 - f1 < MARGIN) {
                    unsigned slot = atomicAdd(counter, 1u);
                    if (slot < (unsigned)flag_cap) flaglist[slot] = blockIdx.x * 128 + lrow;
                }
            }
        }
    __syncthreads();

    // Fused epilogue: arithmetic kept verbatim from the proven version.
    if (tid < 128) {
        const int row = blockIdx.x * 128 + tid;
        const int bi = s_bi[tid];
        const float4* qp = (const float4*)(emb + (size_t)bi * D);
        const float4* xp = (const float4*)(x + (size_t)row * D);
        float4* oq = (float4*)(out_q + (size_t)row * D);
        float l0 = 0.f, l1 = 0.f, l2 = 0.f, l3 = 0.f;
#pragma unroll
        for (int i = 0; i < 16; ++i) {
            float4 q = qp[i];
            float4 xv = xp[i];
            float a0 = q.x - xv.x, a1 = q.y - xv.y, a2 = q.z - xv.z, a3 = q.w - xv.w;
            l0 = fmaf(a0, a0, l0);
            l1 = fmaf(a1, a1, l1);
            l2 = fmaf(a2, a2, l2);
            l3 = fmaf(a3, a3, l3);
            float4 o;
            o.x = xv.x + a0;
            o.y = xv.y + a1;
            o.z = xv.z + a2;
            o.w = xv.w + a3;
            oq[i] = o;
        }
        float s = (l0 + l1) + (l2 + l3);
        out_idx[row] = (float)bi;
        out_loss[row] = s + 0.25f * s;
    }
}

// k2: exact fp32 rescore — ROUND-6 REWRITE. The previous 8-row-batch version
// hit VGPR_Count=256 (d*[8] arrays + full unroll) and scratch-spilled:
// 122 µs at 0.1% VALUBusy. New structure: one flagged row per WAVE.
//   - x row cached in 16 broadcast-loaded float4 registers (64 VGPR, no LDS
//     in the inner loop, no spill; ~120 VGPR total).
//   - each lane sweeps 16 codes (k = c*64 + lane, ascending), per-(row,code)
//     distance arithmetic BIT-IDENTICAL to the proven round-2 formula
//     (same fmaf chains, same (d0+d1)+(d2+d3), same fmaf(-2,.,e2[k]),
//     strict < keeps earliest k per lane).
//   - 64-lane lexicographic (dist, index) shuffle reduce (same tie-break).
//   - loss epilogue keeps the exact s_a 4-chain summation order.
__global__ __launch_bounds__(256) void rescore_kernel(
    const float* __restrict__ x, const float* __restrict__ emb,
    const float* __restrict__ e2, float* __restrict__ out_q,
    float* __restrict__ out_idx, float* __restrict__ out_loss,
    const unsigned int* __restrict__ counter, const int* __restrict__ flaglist,
    int flag_cap) {
    __shared__ float s_a[4][64];
    unsigned int n = *counter;
    if (n > (unsigned)flag_cap) n = (unsigned)flag_cap;
    const int tid = threadIdx.x;
    const int lane = tid & 63;
    const int wv = tid >> 6;
    for (unsigned int base = blockIdx.x * 4u; base < n; base += gridDim.x * 4u) {
        const unsigned fi = base + (unsigned)wv;
        const bool active = fi < n;
        const int row = active ? flaglist[fi] : 0;
        // x row into registers: all lanes load the same addresses -> broadcast.
        float4 xr[16];
        const float4* xp = (const float4*)(x + (size_t)row * D);
#pragma unroll
        for (int i = 0; i < 16; ++i) xr[i] = xp[i];

        float bd = 3.4e38f;
        int bi = 0;
#pragma unroll 4
        for (int c = 0; c < 16; ++c) {
            const int k = c * 64 + lane;   // ascending per lane
            const float4* ekp = (const float4*)(emb + (size_t)k * D);
            float d0 = 0.f, d1 = 0.f, d2 = 0.f, d3 = 0.f;
#pragma unroll
            for (int i = 0; i < 16; ++i) {
                float4 ev = ekp[i];
                float4 xv = xr[i];
                d0 = fmaf(xv.x, ev.x, d0);
                d1 = fmaf(xv.y, ev.y, d1);
                d2 = fmaf(xv.z, ev.z, d2);
                d3 = fmaf(xv.w, ev.w, d3);
            }
            float dist = fmaf(-2.0f, (d0 + d1) + (d2 + d3), e2[k]);
            if (dist < bd) { bd = dist; bi = k; }   // strict <: earliest k wins
        }
        // 64-lane lexicographic (dist, index) butterfly reduce.
#pragma unroll
        for (int mask = 1; mask < 64; mask <<= 1) {
            float ov = __shfl_xor(bd, mask);
            int oi = __shfl_xor(bi, mask);
            bool tk = (ov < bd) || (ov == bd && oi < bi);
            bd = tk ? ov : bd;
            bi = tk ? oi : bi;
        }
        // Epilogue: per-element arithmetic + exact 4-chain loss summation.
        if (active) {
            const float xe = x[(size_t)row * D + lane];
            const float a = emb[(size_t)bi * D + lane] - xe;
            out_q[(size_t)row * D + lane] = xe + a;
            s_a[wv][lane] = a * a;
        }
        __syncthreads();
        if (active && lane == 0) {
            float l0 = 0.f, l1 = 0.f, l2 = 0.f, l3 = 0.f;
            for (int i2 = 0; i2 < 16; ++i2) {
                l0 += s_a[wv][4 * i2 + 0];
                l1 += s_a[wv][4 * i2 + 1];
                l2 += s_a[wv][4 * i2 + 2];
                l3 += s_a[wv][4 * i2 + 3];
            }
            float s = (l0 + l1) + (l2 + l3);
            out_loss[row] = s + 0.25f * s;
            out_idx[row] = (float)bi;
        }
        __syncthreads();
    }
}

extern "C" void kernel_launch(void* const* d_in, const int* in_sizes, int n_in,
                              void* d_out, int out_size, void* d_ws, size_t ws_size,
                              hipStream_t stream) {
    const float* x = (const float*)d_in[0];     // [B,T,D] fp32
    const float* emb = (const float*)d_in[1];   // [K,D] fp32
    const int nrows = in_sizes[0] / D;          // 131072

    float* out_q = (float*)d_out;
    float* out_idx = out_q + (size_t)nrows * D;
    float* out_loss = out_idx + nrows;

    // ws: e2 4KB | e2b 4KB | ehi 128KB | elo 128KB | counter 64B | flaglist
    char* ws = (char*)d_ws;
    float* e2 = (float*)ws;
    float* e2b = (float*)(ws + 4096);
    unsigned short* ehi = (unsigned short*)(ws + 8192);
    unsigned short* elo = (unsigned short*)(ws + 8192 + 131072);
    unsigned int* counter = (unsigned int*)(ws + 8192 + 262144);
    int* flaglist = (int*)(ws + 8192 + 262144 + 64);
    long long avail = (long long)ws_size - (8192 + 262144 + 64);
    int flag_cap = (int)(avail / 4);
    if (flag_cap > 16384) flag_cap = 16384;
    if (flag_cap < 1024) flag_cap = 1024;

    prep_kernel<<<(KCODES * D) / 256, 256, 0, stream>>>(emb, e2, e2b, ehi, elo, counter);
    vq_mfma_kernel<<<nrows / 128, 256, 0, stream>>>(x, emb, e2b, ehi, elo, out_q,
                                                    out_idx, out_loss, counter,
                                                    flaglist, flag_cap);
    rescore_kernel<<<1024, 256, 0, stream>>>(x, emb, e2, out_q, out_idx, out_loss,
                                             counter, flaglist, flag_cap);
}

// Round 10
// 169.860 us; speedup vs baseline: 1.5747x; 1.5566x over previous
//
#include <hip/hip_runtime.h>
#include <hip/hip_bf16.h>

#define D 64
#define KCODES 1024
// Approx-path error budget (distance units), OFFSET=2048 pins values in
// [2048,4096) -> ULP=2.4e-4..4.9e-4:
//   bf16 hi/lo split residual: <=0.025 (proven, prior session, MARGIN 0.25)
// + key quantization: 63*ULP <= 0.015 per value
// + MFMA/C-init rounding at mag ~4096: <= 0.004
// => eps ~= 0.044, 2*eps ~= 0.09 < MARGIN 0.25 (2.8x headroom).
// Near-ties within MARGIN are rescored exactly. Scheme absmax=0.0 on HW
// (rounds 3/5/6); margin 0.25 validated in the prior session.
#define MARGIN 0.25f
#define OFFSET 2048.0f   // approx distance strictly positive => uint-sortable bits

typedef __attribute__((ext_vector_type(8))) short bf16x8;
typedef __attribute__((ext_vector_type(4))) float f32x4;

__device__ __forceinline__ unsigned short f2bf(float f) {
    union { __hip_bfloat16 h; unsigned short s; } cv;
    cv.h = __float2bfloat16(f);
    return cv.s;
}
__device__ __forceinline__ float bf2f(unsigned short v) {
    union { unsigned short s; __hip_bfloat16 h; } cv;
    cv.s = v;
    return __bfloat162float(cv.h);
}

// Direct global->LDS DMA, 16B per lane. LDS dest = wave-uniform base + lane*16.
__device__ __forceinline__ void stage16(const void* g, void* l) {
    __builtin_amdgcn_global_load_lds(
        (const __attribute__((address_space(1))) void*)g,
        (__attribute__((address_space(3))) void*)l, 16, 0, 0);
}

// k0: e2[k] = ||e_k||^2 (exact round-2 arithmetic), e2b = e2 + OFFSET,
// bf16 hi/lo split, zero counter.
__global__ __launch_bounds__(256) void prep_kernel(
    const float* __restrict__ emb, float* __restrict__ e2, float* __restrict__ e2b,
    unsigned short* __restrict__ ehi, unsigned short* __restrict__ elo,
    unsigned int* __restrict__ counter) {
    int t = blockIdx.x * 256 + threadIdx.x;
    if (t == 0) *counter = 0u;
    if (t < KCODES) {
        const float4* ep = (const float4*)(emb + (size_t)t * D);
        float s0 = 0.f, s1 = 0.f, s2 = 0.f, s3 = 0.f;
#pragma unroll
        for (int i = 0; i < 16; ++i) {
            float4 v = ep[i];
            s0 = fmaf(v.x, v.x, s0);
            s1 = fmaf(v.y, v.y, s1);
            s2 = fmaf(v.z, v.z, s2);
            s3 = fmaf(v.w, v.w, s3);
        }
        float s = (s0 + s1) + (s2 + s3);
        e2[t] = s;           // exact, used by rescore
        e2b[t] = s + OFFSET; // biased, approx path / MFMA C-init
    }
    float v = emb[t];
    unsigned short h = f2bf(v);
    ehi[t] = h;
    elo[t] = f2bf(v - bf2f(h));
}

// k1: MFMA distance argmin. Block = 4 waves x 32 rows; grid 1024 => 4 blk/CU.
// Staging via global_load_lds DMA (prev reg-staging was sunk by the scheduler
// next to the ds_write -> serial stage latency inside the barrier window;
// VGPR=64 betrayed the over-aggressive reg minimization). DMA is issued at
// phase TOP (pinned by sched_barrier(0)); __syncthreads' vmcnt drain at phase
// end is then free. Swizzle moved to the per-lane GLOBAL src (rule #21:
// linear LDS dest + inverse-swizzled source + swizzled ds_read).
// MFMA: round-3-validated single 6-chain with C-init = e2b.
__global__ __launch_bounds__(256, 4) void vq_mfma_kernel(
    const float* __restrict__ x, const float* __restrict__ emb,
    const float* __restrict__ e2b, const unsigned short* __restrict__ ehi,
    const unsigned short* __restrict__ elo, float* __restrict__ out_q,
    float* __restrict__ out_idx, float* __restrict__ out_loss,
    unsigned int* __restrict__ counter, int* __restrict__ flaglist, int flag_cap) {
    __shared__ float4 lds4[2][1024];   // 2 x 16KB group buffers
    __shared__ int s_bi[128];
    char* ldsc = (char*)&lds4[0][0];
    const int tid = threadIdx.x;
    const int lane = tid & 63;
    const int wave = __builtin_amdgcn_readfirstlane(tid >> 6);
    const int quad = lane >> 4;
    const int l15 = lane & 15;
    const int rowBase = blockIdx.x * 128 + wave * 32;

    // A fragments: 2 rowsets x 16 rows, pre-scaled by -2 (exact), bf16 hi/lo.
    bf16x8 ah[2][2], al[2][2];
#pragma unroll
    for (int rs = 0; rs < 2; ++rs) {
        const float* xr = x + (size_t)(rowBase + rs * 16 + l15) * D;
#pragma unroll
        for (int c = 0; c < 2; ++c) {
            const float4* p = (const float4*)(xr + c * 32 + quad * 8);
            float4 f0 = p[0], f1 = p[1];
            float f[8] = {f0.x, f0.y, f0.z, f0.w, f1.x, f1.y, f1.z, f1.w};
            bf16x8 h, l;
#pragma unroll
            for (int j = 0; j < 8; ++j) {
                float v = -2.0f * f[j];
                unsigned short hu = f2bf(v);
                h[j] = (short)hu;
                l[j] = (short)f2bf(v - bf2f(hu));   // exact (Sterbenz)
            }
            ah[rs][c] = h;
            al[rs][c] = l;
        }
    }

    // DMA staging: group = 16KB = [h:2][row:64][slot:8] 16B units, linear.
    // Wave w covers linear 16B-unit index li = w*256 + i*64 + lane (i=0..3).
    // Physical slot s of row r holds logical slot s^(r&7): global src reads
    // logical slot (s^(r&7)) -> ds_read side XOR stays identical to the
    // HW-validated rounds 5/6.
    const unsigned short* gs[4];
#pragma unroll
    for (int i = 0; i < 4; ++i) {
        int li = wave * 256 + i * 64 + lane;
        int h = li >> 9, row = (li >> 3) & 63, sl = li & 7;
        gs[i] = (h ? elo : ehi) + row * 64 + (sl ^ (row & 7)) * 8;
    }
    char* wlds0 = ldsc + wave * 4096;   // + buf*16384 + i*1024

    // ds_read offsets (swizzled), unchanged from rounds 5/6.
    const int s7 = l15 & 7;
    const int rdA0 = l15 * 128 + ((quad ^ s7) << 4);
    const int rdB0 = l15 * 128 + (((quad + 4) ^ s7) << 4);

    unsigned int m1[2][4], m2[2][4];
#pragma unroll
    for (int rs = 0; rs < 2; ++rs)
#pragma unroll
        for (int r = 0; r < 4; ++r) { m1[rs][r] = 0xFFFFFFFFu; m2[rs][r] = 0xFFFFFFFFu; }

    // Prologue: DMA group 0 -> buf0; group-0 e2b.
#pragma unroll
    for (int i = 0; i < 4; ++i) stage16(gs[i], wlds0 + i * 1024);
    float e2v[4];
#pragma unroll
    for (int tg = 0; tg < 4; ++tg) e2v[tg] = e2b[tg * 16 + l15];
    __syncthreads();   // drains vmcnt -> buf0 valid

#pragma unroll 1
    for (int g = 0; g < 16; ++g) {
        // Phase top: issue next-group DMA + e2b prefetch, pinned before compute.
        float e2n[4];
        if (g < 15) {
            char* wb = wlds0 + (((g + 1) & 1) << 14);
#pragma unroll
            for (int i = 0; i < 4; ++i)
                stage16(gs[i] + (size_t)(g + 1) * 4096, wb + i * 1024);
#pragma unroll
            for (int tg = 0; tg < 4; ++tg)
                e2n[tg] = e2b[(g + 1) * 64 + tg * 16 + l15];
        }
        __builtin_amdgcn_sched_barrier(0);
        const char* rb = ldsc + ((g & 1) << 14);
#pragma unroll
        for (int tg = 0; tg < 4; ++tg) {
            bf16x8 bh0 = *(const bf16x8*)(rb + rdA0 + tg * 2048);
            bf16x8 bh1 = *(const bf16x8*)(rb + rdB0 + tg * 2048);
            bf16x8 bl0 = *(const bf16x8*)(rb + 8192 + rdA0 + tg * 2048);
            bf16x8 bl1 = *(const bf16x8*)(rb + 8192 + rdB0 + tg * 2048);
            const unsigned tt = (unsigned)(g * 4 + tg);
            const float ev = e2v[tg];
            f32x4 c0 = {ev, ev, ev, ev};   // C-init: col(code)=l15, all 4 rows
#pragma unroll
            for (int rs = 0; rs < 2; ++rs) {
                // Single 6-MFMA chain (round-3-validated): hi*hi + lo*hi + hi*lo
                // per K-chunk; lo*lo below threshold, omitted.
                f32x4 acc = c0;
                acc = __builtin_amdgcn_mfma_f32_16x16x32_bf16(ah[rs][0], bh0, acc, 0, 0, 0);
                acc = __builtin_amdgcn_mfma_f32_16x16x32_bf16(al[rs][0], bh0, acc, 0, 0, 0);
                acc = __builtin_amdgcn_mfma_f32_16x16x32_bf16(ah[rs][0], bl0, acc, 0, 0, 0);
                acc = __builtin_amdgcn_mfma_f32_16x16x32_bf16(ah[rs][1], bh1, acc, 0, 0, 0);
                acc = __builtin_amdgcn_mfma_f32_16x16x32_bf16(al[rs][1], bh1, acc, 0, 0, 0);
                acc = __builtin_amdgcn_mfma_f32_16x16x32_bf16(ah[rs][1], bl1, acc, 0, 0, 0);
#pragma unroll
                for (int r = 0; r < 4; ++r) {
                    unsigned k = (__float_as_uint(acc[r]) & 0xFFFFFFC0u) | tt;
                    unsigned nm2;
                    asm("v_med3_u32 %0, %1, %2, %3"
                        : "=v"(nm2)
                        : "v"(m1[rs][r]), "v"(m2[rs][r]), "v"(k));
                    m2[rs][r] = nm2;                       // exact new 2nd-min
                    m1[rs][r] = (k < m1[rs][r]) ? k : m1[rs][r];
                }
            }
        }
        if (g < 15) {
#pragma unroll
            for (int tg = 0; tg < 4; ++tg) e2v[tg] = e2n[tg];
        }
        __syncthreads();   // drains MY DMA (vmcnt 0) + releases buffers
    }

    // Cross-lane merge over the 16 code-lanes; winner lane via ballot.
    // All key-level ties/near-ties satisfy m2-m1 < MARGIN => rescored exactly.
#pragma unroll
    for (int rs = 0; rs < 2; ++rs)
#pragma unroll
        for (int r = 0; r < 4; ++r) {
            unsigned v1 = m1[rs][r], v2 = m2[rs][r];
            const unsigned my1 = v1;
#pragma unroll
            for (int mask = 1; mask < 16; mask <<= 1) {
                unsigned o1 = __shfl_xor(v1, mask);
                unsigned o2 = __shfl_xor(v2, mask);
                unsigned hi = v1 > o1 ? v1 : o1;
                unsigned lo2 = v2 < o2 ? v2 : o2;
                v2 = lo2 < hi ? lo2 : hi;   // union 2nd-min
                v1 = v1 < o1 ? v1 : o1;
            }
            unsigned long long bal = __ballot(my1 == v1);
            int winl = __ffsll((bal >> (quad * 16)) & 0xFFFFull) - 1;
            int code = (int)(v1 & 63u) * 16 + winl;
            if (l15 == 0) {
                int lrow = wave * 32 + rs * 16 + quad * 4 + r;
                s_bi[lrow] = code;
                float f1 = __uint_as_float(v1 & 0xFFFFFFC0u);
                float f2 = __uint_as_float(v2 & 0xFFFFFFC0u);
                if (f2 - f1 < MARGIN) {
                    unsigned slot = atomicAdd(counter, 1u);
                    if (slot < (unsigned)flag_cap) flaglist[slot] = blockIdx.x * 128 + lrow;
                }
            }
        }
    __syncthreads();

    // Fused epilogue: arithmetic verbatim from the proven version.
    if (tid < 128) {
        const int row = blockIdx.x * 128 + tid;
        const int bi = s_bi[tid];
        const float4* qp = (const float4*)(emb + (size_t)bi * D);
        const float4* xp = (const float4*)(x + (size_t)row * D);
        float4* oq = (float4*)(out_q + (size_t)row * D);
        float l0 = 0.f, l1 = 0.f, l2 = 0.f, l3 = 0.f;
#pragma unroll
        for (int i = 0; i < 16; ++i) {
            float4 q = qp[i];
            float4 xv = xp[i];
            float a0 = q.x - xv.x, a1 = q.y - xv.y, a2 = q.z - xv.z, a3 = q.w - xv.w;
            l0 = fmaf(a0, a0, l0);
            l1 = fmaf(a1, a1, l1);
            l2 = fmaf(a2, a2, l2);
            l3 = fmaf(a3, a3, l3);
            float4 o;
            o.x = xv.x + a0;
            o.y = xv.y + a1;
            o.z = xv.z + a2;
            o.w = xv.w + a3;
            oq[i] = o;
        }
        float s = (l0 + l1) + (l2 + l3);
        out_idx[row] = (float)bi;
        out_loss[row] = s + 0.25f * s;
    }
}

// k2: exact fp32 rescore, 8 rows per block-batch (codebook swept once per 8
// rows). Round-5 proven arithmetic; spill fixed with #pragma unroll 1 on the
// dim loop (full 16x8 unroll previously drove VGPR to 256 + scratch).
__global__ __launch_bounds__(256) void rescore_kernel(
    const float* __restrict__ x, const float* __restrict__ emb,
    const float* __restrict__ e2, float* __restrict__ out_q,
    float* __restrict__ out_idx, float* __restrict__ out_loss,
    const unsigned int* __restrict__ counter, const int* __restrict__ flaglist,
    int flag_cap) {
    __shared__ float s_x[8][64];
    __shared__ int s_rows[8];
    __shared__ float s_wd[8][4];
    __shared__ int s_wi[8][4];
    __shared__ float s_a[4][64];
    unsigned int n = *counter;
    if (n > (unsigned)flag_cap) n = (unsigned)flag_cap;
    const int tid = threadIdx.x;
    const int lane = tid & 63;
    const int wv = tid >> 6;
    for (unsigned int b = blockIdx.x; b * 8u < n; b += gridDim.x) {
        const unsigned base = b * 8u;
        unsigned nbu = n - base;
        if (nbu > 8u) nbu = 8u;
        const int nb = (int)nbu;
        if (tid < 8) s_rows[tid] = flaglist[base + (tid < nb ? tid : 0)];
        __syncthreads();
        if (tid < 128) {
            int r = tid >> 4, q4 = tid & 15;
            ((float4*)&s_x[r][0])[q4] = ((const float4*)(x + (size_t)s_rows[r] * D))[q4];
        }
        __syncthreads();

        float bd_[8];
        int bi_[8];
#pragma unroll
        for (int r = 0; r < 8; ++r) { bd_[r] = 3.4e38f; bi_[r] = 0; }
#pragma unroll 1
        for (int kk = 0; kk < 4; ++kk) {
            const int k = tid + kk * 256;   // ascending per thread
            const float4* ekp = (const float4*)(emb + (size_t)k * D);
            float d0[8], d1[8], d2[8], d3[8];
#pragma unroll
            for (int r = 0; r < 8; ++r) { d0[r] = 0.f; d1[r] = 0.f; d2[r] = 0.f; d3[r] = 0.f; }
#pragma unroll 1
            for (int i = 0; i < 16; ++i) {     // rolled: caps live LDS loads
                float4 ev = ekp[i];
#pragma unroll
                for (int r = 0; r < 8; ++r) {
                    float4 xv = ((const float4*)&s_x[r][0])[i];   // LDS broadcast
                    d0[r] = fmaf(xv.x, ev.x, d0[r]);
                    d1[r] = fmaf(xv.y, ev.y, d1[r]);
                    d2[r] = fmaf(xv.z, ev.z, d2[r]);
                    d3[r] = fmaf(xv.w, ev.w, d3[r]);
                }
            }
            float e2k = e2[k];
#pragma unroll
            for (int r = 0; r < 8; ++r) {
                float dist = fmaf(-2.0f, (d0[r] + d1[r]) + (d2[r] + d3[r]), e2k);
                if (dist < bd_[r]) { bd_[r] = dist; bi_[r] = k; }
            }
        }
        // reduce: wave shuffle then cross-wave, lexicographic (dist, index)
#pragma unroll
        for (int r = 0; r < 8; ++r) {
            float v = bd_[r];
            int ix = bi_[r];
#pragma unroll
            for (int mask = 1; mask < 64; mask <<= 1) {
                float ov = __shfl_xor(v, mask);
                int oi = __shfl_xor(ix, mask);
                bool tk = (ov < v) || (ov == v && oi < ix);
                v = tk ? ov : v;
                ix = tk ? oi : ix;
            }
            if (lane == 0) { s_wd[r][wv] = v; s_wi[r][wv] = ix; }
        }
        __syncthreads();
        if (tid < 8) {
            float v = s_wd[tid][0];
            int ix = s_wi[tid][0];
#pragma unroll
            for (int w = 1; w < 4; ++w) {
                float ov = s_wd[tid][w];
                int oi = s_wi[tid][w];
                bool tk = (ov < v) || (ov == v && oi < ix);
                v = tk ? ov : v;
                ix = tk ? oi : ix;
            }
            s_wi[tid][0] = ix;
        }
        __syncthreads();
        // epilogue: 2 passes x 4 rows; original per-element + summation order.
#pragma unroll
        for (int pass = 0; pass < 2; ++pass) {
            const int rloc = pass * 4 + wv;
            const int row = s_rows[rloc];
            const int fbi = s_wi[rloc][0];
            const float xe = s_x[rloc][lane];
            const float a = emb[(size_t)fbi * D + lane] - xe;
            if (rloc < nb) out_q[(size_t)row * D + lane] = xe + a;
            s_a[wv][lane] = a * a;
            __syncthreads();
            if (lane == 0 && rloc < nb) {
                float l0 = 0.f, l1 = 0.f, l2 = 0.f, l3 = 0.f;
                for (int i2 = 0; i2 < 16; ++i2) {
                    l0 += s_a[wv][4 * i2 + 0];
                    l1 += s_a[wv][4 * i2 + 1];
                    l2 += s_a[wv][4 * i2 + 2];
                    l3 += s_a[wv][4 * i2 + 3];
                }
                float s = (l0 + l1) + (l2 + l3);
                out_loss[row] = s + 0.25f * s;
                out_idx[row] = (float)fbi;
            }
            __syncthreads();
        }
    }
}

extern "C" void kernel_launch(void* const* d_in, const int* in_sizes, int n_in,
                              void* d_out, int out_size, void* d_ws, size_t ws_size,
                              hipStream_t stream) {
    const float* x = (const float*)d_in[0];     // [B,T,D] fp32
    const float* emb = (const float*)d_in[1];   // [K,D] fp32
    const int nrows = in_sizes[0] / D;          // 131072

    float* out_q = (float*)d_out;
    float* out_idx = out_q + (size_t)nrows * D;
    float* out_loss = out_idx + nrows;

    // ws: e2 4KB | e2b 4KB | ehi 128KB | elo 128KB | counter 64B | flaglist
    char* ws = (char*)d_ws;
    float* e2 = (float*)ws;
    float* e2b = (float*)(ws + 4096);
    unsigned short* ehi = (unsigned short*)(ws + 8192);
    unsigned short* elo = (unsigned short*)(ws + 8192 + 131072);
    unsigned int* counter = (unsigned int*)(ws + 8192 + 262144);
    int* flaglist = (int*)(ws + 8192 + 262144 + 64);
    long long avail = (long long)ws_size - (8192 + 262144 + 64);
    int flag_cap = (int)(avail / 4);
    if (flag_cap > 16384) flag_cap = 16384;
    if (flag_cap < 1024) flag_cap = 1024;

    prep_kernel<<<(KCODES * D) / 256, 256, 0, stream>>>(emb, e2, e2b, ehi, elo, counter);
    vq_mfma_kernel<<<nrows / 128, 256, 0, stream>>>(x, emb, e2b, ehi, elo, out_q,
                                                    out_idx, out_loss, counter,
                                                    flaglist, flag_cap);
    rescore_kernel<<<1024, 256, 0, stream>>>(x, emb, e2, out_q, out_idx, out_loss,
                                             counter, flaglist, flag_cap);
}